// Round 3
// baseline (95.143 us; speedup 1.0000x reference)
//
#include <hip/hip_runtime.h>
#include <math.h>

#define MAXP 32

// one point: raw sums (reference sums padding too) + masked max.
// Padded points (p >= np) substitute point-0 data: v == v_0, max unchanged,
// and the select is uniform -> SALU s_cselect (free alongside VALU).
#define PT(p, qq, mm) do {                                                  \
    sx += (qq).x; sy += (qq).y; sz += (qq).z;                               \
    const float xx_ = ((p) < np) ? (qq).x : qdup.x;                         \
    const float yy_ = ((p) < np) ? (qq).y : qdup.y;                         \
    const float zz_ = ((p) < np) ? (qq).z : qdup.z;                         \
    const float ww_ = ((p) < np) ? (qq).w : qdup.w;                         \
    const float vv_ = fmaf(xx_, A, fmaf(yy_, B, fmaf(zz_, C,                \
                         fmaf(ww_, Dk, E2))));                              \
    mm = fmaxf(mm, vv_);                                                    \
} while (0)

__global__ __launch_bounds__(256, 8) void pfn_kernel(
    const float* __restrict__ voxels,
    const int*   __restrict__ num_points,
    const int*   __restrict__ coords,
    const float* __restrict__ W,
    const float* __restrict__ gamma,
    const float* __restrict__ beta,
    const float* __restrict__ rmean,
    const float* __restrict__ rvar,
    float*       __restrict__ out,
    int N)
{
    const int lane = threadIdx.x & 63;
    const int wid  = threadIdx.x >> 6;

    // ---- per-lane (= per output channel) constants: once per wave ----
    const int d = lane;
    const float w0 = W[0*64+d], w1 = W[1*64+d], w2 = W[2*64+d];
    const float w3 = W[3*64+d], w4 = W[4*64+d], w5 = W[5*64+d];
    const float w6 = W[6*64+d], w7 = W[7*64+d], w8 = W[8*64+d];
    const float inv   = gamma[d] * rsqrtf(rvar[d] + 1e-3f);
    const float shift = fmaf(-rmean[d], inv, beta[d]);
    const float A  = (w0 + w4 + w7) * inv;   // coeff of x
    const float B  = (w1 + w5 + w8) * inv;   // coeff of y
    const float C  = (w2 + w6) * inv;        // coeff of z
    const float Dk = w3 * inv;               // coeff of w
    const float P4 = w4 * inv, P5 = w5 * inv, P6 = w6 * inv;
    const float P7 = w7 * inv, P8 = w8 * inv;

    const int wave = blockIdx.x * 4 + wid;   // 4 waves / 256-thr block

    for (int k = 0; k < 2; ++k) {            // 2 pillars per wave
        const int pr = wave * 2 + k;
        if (pr >= N) return;
        const int pillar = __builtin_amdgcn_readfirstlane(pr);

        // wave-uniform addresses -> scalar (SMEM) loads into SGPRs
        const float4* bp = (const float4*)(voxels + (size_t)pillar * (MAXP * 4));
        const int np = __builtin_amdgcn_readfirstlane(num_points[pillar]);
        const int c0 = coords[pillar * 3 + 0];
        const int c1 = coords[pillar * 3 + 1];
        const float cx = fmaf((float)c0, 0.2f, 0.1f);    // VX/2 + 0
        const float cy = fmaf((float)c1, 0.2f, -25.5f);  // VY/2 - 25.6
        const float E2 = shift - cx * P7 - cy * P8;      // excludes mean term

        float sx = 0.f, sy = 0.f, sz = 0.f;
        float m0 = -INFINITY, m1 = -INFINITY, m2 = -INFINITY, m3 = -INFINITY;
        float4 q[8];
        float4 qdup;

        // ---- group 0: points 0..7 (always; np >= 1) ----
        #pragma unroll
        for (int j = 0; j < 8; ++j) q[j] = bp[j];
        qdup = q[0];
        PT(0, q[0], m0); PT(1, q[1], m1); PT(2, q[2], m2); PT(3, q[3], m3);
        PT(4, q[4], m0); PT(5, q[5], m1); PT(6, q[6], m2); PT(7, q[7], m3);

        // ---- group 1: points 8..15 ----
        #pragma unroll
        for (int j = 0; j < 8; ++j) q[j] = bp[8 + j];
        if (np > 8) {
            PT( 8, q[0], m0); PT( 9, q[1], m1); PT(10, q[2], m2); PT(11, q[3], m3);
            PT(12, q[4], m0); PT(13, q[5], m1); PT(14, q[6], m2); PT(15, q[7], m3);
        } else {
            #pragma unroll
            for (int j = 0; j < 8; ++j) { sx += q[j].x; sy += q[j].y; sz += q[j].z; }
        }

        // ---- group 2: points 16..23 ----
        #pragma unroll
        for (int j = 0; j < 8; ++j) q[j] = bp[16 + j];
        if (np > 16) {
            PT(16, q[0], m0); PT(17, q[1], m1); PT(18, q[2], m2); PT(19, q[3], m3);
            PT(20, q[4], m0); PT(21, q[5], m1); PT(22, q[6], m2); PT(23, q[7], m3);
        } else {
            #pragma unroll
            for (int j = 0; j < 8; ++j) { sx += q[j].x; sy += q[j].y; sz += q[j].z; }
        }

        // ---- group 3: points 24..31 ----
        #pragma unroll
        for (int j = 0; j < 8; ++j) q[j] = bp[24 + j];
        if (np > 24) {
            PT(24, q[0], m0); PT(25, q[1], m1); PT(26, q[2], m2); PT(27, q[3], m3);
            PT(28, q[4], m0); PT(29, q[5], m1); PT(30, q[6], m2); PT(31, q[7], m3);
        } else {
            #pragma unroll
            for (int j = 0; j < 8; ++j) { sx += q[j].x; sy += q[j].y; sz += q[j].z; }
        }

        // ---- epilogue: subtract deferred mean term, fold padded value, relu ----
        const float mv  = fmaxf(fmaxf(m0, m1), fmaxf(m2, m3));
        const float rnf = 1.0f / (float)np;
        const float S   = fmaf(sx, P4, fmaf(sy, P5, sz * P6)) * rnf;
        float mfin = mv - S;
        if (np < MAXP) mfin = fmaxf(mfin, shift);  // padded points contribute `shift`
        out[(size_t)pillar * 64 + d] = fmaxf(mfin, 0.0f);
    }
}

extern "C" void kernel_launch(void* const* d_in, const int* in_sizes, int n_in,
                              void* d_out, int out_size, void* d_ws, size_t ws_size,
                              hipStream_t stream) {
    const float* voxels     = (const float*)d_in[0];
    const int*   num_points = (const int*)  d_in[1];
    const int*   coords     = (const int*)  d_in[2];
    const float* W          = (const float*)d_in[3];
    const float* gamma      = (const float*)d_in[4];
    const float* beta       = (const float*)d_in[5];
    const float* rmean      = (const float*)d_in[6];
    const float* rvar       = (const float*)d_in[7];
    float*       out        = (float*)d_out;

    const int N = in_sizes[1];              // num_points: one entry per pillar
    const int pillars_per_block = 4 * 2;    // 4 waves x 2 pillars
    const int blocks = (N + pillars_per_block - 1) / pillars_per_block;
    pfn_kernel<<<blocks, 256, 0, stream>>>(voxels, num_points, coords, W,
                                           gamma, beta, rmean, rvar, out, N);
}

// Round 4
// 37.307 us; speedup vs baseline: 2.5503x; 2.5503x over previous
//
#include <hip/hip_runtime.h>
#include <math.h>

#define MAXP 32

__device__ __forceinline__ float rdlanef(float v, int l) {
    return __int_as_float(__builtin_amdgcn_readlane(__float_as_int(v), l));
}

// one point, select-form: pidx/np uniform -> s_cmp + one v_cndmask + max
#define PTSEL(qarr, j, pidx) do {                                   \
    float v_ = fmaf(qarr[4*(j)+0], A, E2);                          \
    v_ = fmaf(qarr[4*(j)+1], B, v_);                                \
    v_ = fmaf(qarr[4*(j)+2], C, v_);                                \
    v_ = fmaf(qarr[4*(j)+3], Dk, v_);                               \
    m = fmaxf(m, ((pidx) < np) ? v_ : -INFINITY);                   \
} while (0)

__global__ __launch_bounds__(256, 8) void pfn_kernel(
    const float* __restrict__ voxels,
    const int*   __restrict__ num_points,
    const int*   __restrict__ coords,
    const float* __restrict__ W,
    const float* __restrict__ gammav,
    const float* __restrict__ betav,
    const float* __restrict__ rmean,
    const float* __restrict__ rvar,
    float*       __restrict__ out,
    int N)
{
    const int lane = threadIdx.x & 63;
    const int wid  = threadIdx.x >> 6;
    const int d    = lane;

    // ---- per-lane (= per channel) constants, amortized over 8 pillars ----
    const float w0 = W[0*64+d], w1 = W[1*64+d], w2 = W[2*64+d];
    const float w3 = W[3*64+d], w4 = W[4*64+d], w5 = W[5*64+d];
    const float w6 = W[6*64+d], w7 = W[7*64+d], w8 = W[8*64+d];
    const float inv   = gammav[d] * rsqrtf(rvar[d] + 1e-3f);
    const float shift = fmaf(-rmean[d], inv, betav[d]);
    const float A  = (w0 + w4 + w7) * inv;
    const float B  = (w1 + w5 + w8) * inv;
    const float C  = (w2 + w6) * inv;
    const float Dk = w3 * inv;
    const float P4 = w4 * inv, P5 = w5 * inv, P6 = w6 * inv;
    const float P7 = w7 * inv, P8 = w8 * inv;

    const int base = blockIdx.x * 32 + wid * 8;   // 8 pillars per wave

    auto processPillar = [&](int sp, float sx, float sy, float sz) {
        const float* __restrict__ bp = voxels + (size_t)sp * 128;  // uniform -> SMEM
        const int np = __builtin_amdgcn_readfirstlane(num_points[sp]);
        const int c0 = coords[sp*3 + 0];
        const int c1 = coords[sp*3 + 1];
        const float cx = fmaf((float)c0, 0.2f, 0.1f);    // VX/2 + 0
        const float cy = fmaf((float)c1, 0.2f, -25.5f);  // VY/2 - 25.6
        const float E2 = shift - cx*P7 - cy*P8;          // mean term deferred

        float qa[32], qb[32];                    // ping-pong SGPR windows
        #pragma unroll
        for (int i = 0; i < 32; ++i) qa[i] = bp[i];        // pts 0..7
        #pragma unroll
        for (int i = 0; i < 32; ++i) qb[i] = bp[32 + i];   // pts 8..15

        float m = -INFINITY;
        // window 0 (always: np >= 1)
        PTSEL(qa,0,0); PTSEL(qa,1,1); PTSEL(qa,2,2); PTSEL(qa,3,3);
        PTSEL(qa,4,4); PTSEL(qa,5,5); PTSEL(qa,6,6); PTSEL(qa,7,7);

        #pragma unroll
        for (int i = 0; i < 32; ++i) qa[i] = bp[64 + i];   // pts 16..23

        if (np > 8) {
            PTSEL(qb,0, 8); PTSEL(qb,1, 9); PTSEL(qb,2,10); PTSEL(qb,3,11);
            PTSEL(qb,4,12); PTSEL(qb,5,13); PTSEL(qb,6,14); PTSEL(qb,7,15);
        }

        #pragma unroll
        for (int i = 0; i < 32; ++i) qb[i] = bp[96 + i];   // pts 24..31

        if (np > 16) {
            PTSEL(qa,0,16); PTSEL(qa,1,17); PTSEL(qa,2,18); PTSEL(qa,3,19);
            PTSEL(qa,4,20); PTSEL(qa,5,21); PTSEL(qa,6,22); PTSEL(qa,7,23);
        }
        if (np > 24) {
            PTSEL(qb,0,24); PTSEL(qb,1,25); PTSEL(qb,2,26); PTSEL(qb,3,27);
            PTSEL(qb,4,28); PTSEL(qb,5,29); PTSEL(qb,6,30); PTSEL(qb,7,31);
        }

        // deferred mean term (S_d is p-independent -> subtract after max)
        const float S = fmaf(sx, P4, fmaf(sy, P5, sz * P6)) / (float)np;
        float mf = m - S;
        if (np < MAXP) mf = fmaxf(mf, shift);   // padded points contribute `shift`
        out[(size_t)sp * 64 + d] = fmaxf(mf, 0.0f);
    };

    #pragma unroll 1
    for (int pr = 0; pr < 4; ++pr) {            // pillar pairs (A,B)
        const int pA = base + 2*pr;
        if (pA >= N) return;
        const int pB = pA + 1;
        const int sA = __builtin_amdgcn_readfirstlane(pA);
        const int sB = __builtin_amdgcn_readfirstlane(pB < N ? pB : pA);

        // ---- butterfly xyz sums: lanes 0-31 cover A's 32 pts, 32-63 cover B's ----
        const size_t off = (size_t)((lane < 32) ? sA : sB) * 128 + (size_t)(lane & 31) * 4;
        const float4 f = *(const float4*)(voxels + off);
        float bx = f.x, by = f.y, bz = f.z;
        #pragma unroll
        for (int msk = 1; msk <= 16; msk <<= 1) {   // stays within 32-lane halves
            bx += __shfl_xor(bx, msk);
            by += __shfl_xor(by, msk);
            bz += __shfl_xor(bz, msk);
        }
        const float sxA = rdlanef(bx, 0),  syA = rdlanef(by, 0),  szA = rdlanef(bz, 0);
        const float sxB = rdlanef(bx, 32), syB = rdlanef(by, 32), szB = rdlanef(bz, 32);

        processPillar(sA, sxA, syA, szA);
        if (pB < N) processPillar(sB, sxB, syB, szB);
    }
}

extern "C" void kernel_launch(void* const* d_in, const int* in_sizes, int n_in,
                              void* d_out, int out_size, void* d_ws, size_t ws_size,
                              hipStream_t stream) {
    const float* voxels     = (const float*)d_in[0];
    const int*   num_points = (const int*)  d_in[1];
    const int*   coords     = (const int*)  d_in[2];
    const float* W          = (const float*)d_in[3];
    const float* gammav     = (const float*)d_in[4];
    const float* betav      = (const float*)d_in[5];
    const float* rmean      = (const float*)d_in[6];
    const float* rvar       = (const float*)d_in[7];
    float*       out        = (float*)d_out;

    const int N = in_sizes[1];                  // one entry per pillar
    const int blocks = (N + 31) / 32;           // 32 pillars per 256-thr block
    pfn_kernel<<<blocks, 256, 0, stream>>>(voxels, num_points, coords, W,
                                           gammav, betav, rmean, rvar, out, N);
}